// Round 16
// baseline (769.558 us; speedup 1.0000x reference)
//
#include <hip/hip_runtime.h>

#define B_    128
#define A_    4
#define N_    128
#define F_IN_ 16
#define H_    256
#define HEADS_ 4
#define FF_   512
#define OUT_  64
#define BF_   3
#define L_    2
#define T_    512          // B*A
#define E_    127          // N-1
#define DH_   64
#define P_    384          // N*BF
#define TOK_  65536        // T*N

typedef unsigned short u16;
typedef __attribute__((ext_vector_type(8))) short bf16x8;   // 8 bf16 = 4 VGPR
typedef __attribute__((ext_vector_type(4))) float f32x4;

__device__ __forceinline__ float u2f(u16 u) {
    return __uint_as_float(((unsigned)u) << 16);
}
__device__ __forceinline__ u16 f2bf(float f) {
    unsigned u = __float_as_uint(f);
    unsigned r = (u + 0x7fffu + ((u >> 16) & 1u)) >> 16;
    return (u16)r;
}

// ---------------------------------------------------------------------------
// fp32 -> bf16 weight conversion (grid-stride)
// ---------------------------------------------------------------------------
__global__ __launch_bounds__(256) void k_cvt(
        const float* __restrict__ src, u16* __restrict__ dst, int n)
{
    for (int i = blockIdx.x * 256 + threadIdx.x; i < n; i += gridDim.x * 256)
        dst[i] = f2bf(src[i]);
}

// ---------------------------------------------------------------------------
// init-weight prep (verified R13)
// ---------------------------------------------------------------------------
__global__ __launch_bounds__(256) void k_prep(
        const float* __restrict__ W_in, const float* __restrict__ b_in,
        const float* __restrict__ b_pos, const float* __restrict__ W_pos,
        float* __restrict__ W_inT, float* __restrict__ W_posT,
        float* __restrict__ bsum)
{
    int i = blockIdx.x * 256 + threadIdx.x;
    if (i < 4096) W_inT[(i & 15) * 256 + (i >> 4)] = W_in[i];
    if (i < 4096) {
        int p = i >> 8, h = i & 255;
        W_posT[i] = W_pos[(size_t)h * P_ + p];
    }
    if (i < 256) bsum[i] = b_in[i] + b_pos[i];
}

// ---------------------------------------------------------------------------
// pos bitmask per node (verified R14)
// ---------------------------------------------------------------------------
__global__ __launch_bounds__(256) void k_pos(
        const int* __restrict__ adj, int* __restrict__ mask)
{
    int tn = blockIdx.x * 256 + threadIdx.x;
    if (tn >= TOK_) return;
    int t = tn >> 7;
    int n = tn & 127;

    int slots[8];
    int nb = 0;
    int c = n;
    while (c > 0 && nb < 8) {
        const int* e = adj + ((size_t)t * E_ + (c - 1)) * 3;
        int pg = e[0];
        int sl = e[2] + 1;
        sl = sl < 0 ? 0 : (sl > 2 ? 2 : sl);
        slots[nb++] = sl;
        c = pg - t * N_;
    }
    int mk = 0;
    for (int i = 0; i < nb; ++i)
        mk |= 1 << ((nb - 1 - i) * BF_ + slots[i]);
    mask[tn] = mk;
}

// ---------------------------------------------------------------------------
// x0 init, coalesced (verified R13)
// ---------------------------------------------------------------------------
__global__ __launch_bounds__(256) void k_init_x(
        const float* __restrict__ forest, const int* __restrict__ mask,
        const float* __restrict__ W_inT, const float* __restrict__ W_posT,
        const float* __restrict__ bsum, u16* __restrict__ x)
{
    int h = threadIdx.x;
    int t0 = blockIdx.x * 4;

    float wf[16];
#pragma unroll
    for (int f = 0; f < F_IN_; ++f) wf[f] = W_inT[f * 256 + h];
    float bs = bsum[h];

#pragma unroll
    for (int tt = 0; tt < 4; ++tt) {
        int tn = t0 + tt;
        const float* fr = forest + (size_t)tn * F_IN_;
        float acc = bs;
#pragma unroll
        for (int f = 0; f < F_IN_; ++f) acc += fr[f] * wf[f];
        unsigned mk = (unsigned)mask[tn];
        while (mk) {
            int bit = __ffs(mk) - 1;
            mk &= mk - 1;
            acc += W_posT[bit * 256 + h];
        }
        x[(size_t)tn * H_ + h] = f2bf(acc);
    }
}

// ---------------------------------------------------------------------------
// MFMA GEMM (verified R11) — proj / ff1 / ff2.
// ---------------------------------------------------------------------------
__global__ __launch_bounds__(256) void k_gemm_mfma(
        const u16* __restrict__ A, int lda,
        const u16* __restrict__ Bw, int ldb,
        const float* __restrict__ bias, size_t biasoff,
        u16* __restrict__ C, int ldc,
        int K, int relu)
{
    __shared__ __align__(16) u16 As[128][40];
    __shared__ __align__(16) u16 Bs[128][40];

    int tid = threadIdx.x;
    int wid = tid >> 6, lane = tid & 63;
    int ln15 = lane & 15, quad = lane >> 4;
    int wm = (wid >> 1) * 64, wn = (wid & 1) * 64;
    size_t m0 = (size_t)blockIdx.x * 128;
    size_t n0 = (size_t)blockIdx.y * 128;

    f32x4 acc[4][4];
#pragma unroll
    for (int i = 0; i < 4; ++i)
#pragma unroll
        for (int j = 0; j < 4; ++j)
#pragma unroll
            for (int r = 0; r < 4; ++r) acc[i][j][r] = 0.f;

    for (int k0 = 0; k0 < K; k0 += 32) {
        __syncthreads();
#pragma unroll
        for (int s = 0; s < 2; ++s) {
            int idx = tid + s * 256;
            int r = idx >> 2;
            int kq = (idx & 3) * 8;
            *reinterpret_cast<uint4*>(&As[r][kq]) =
                *reinterpret_cast<const uint4*>(&A[(m0 + r) * (size_t)lda + k0 + kq]);
            *reinterpret_cast<uint4*>(&Bs[r][kq]) =
                *reinterpret_cast<const uint4*>(&Bw[(n0 + r) * (size_t)ldb + k0 + kq]);
        }
        __syncthreads();

        bf16x8 af[4], bfr[4];
#pragma unroll
        for (int i = 0; i < 4; ++i)
            af[i] = *reinterpret_cast<const bf16x8*>(&As[wm + i * 16 + ln15][quad * 8]);
#pragma unroll
        for (int j = 0; j < 4; ++j)
            bfr[j] = *reinterpret_cast<const bf16x8*>(&Bs[wn + j * 16 + ln15][quad * 8]);
#pragma unroll
        for (int i = 0; i < 4; ++i)
#pragma unroll
            for (int j = 0; j < 4; ++j)
                acc[i][j] = __builtin_amdgcn_mfma_f32_16x16x32_bf16(
                    af[i], bfr[j], acc[i][j], 0, 0, 0);
    }

#pragma unroll
    for (int i = 0; i < 4; ++i) {
#pragma unroll
        for (int j = 0; j < 4; ++j) {
            int col = (int)n0 + wn + j * 16 + ln15;
            float bv = bias ? bias[biasoff + col] : 0.f;
#pragma unroll
            for (int r = 0; r < 4; ++r) {
                int row = (int)m0 + wm + i * 16 + quad * 4 + r;
                float v = acc[i][j][r] + bv;
                if (relu) v = fmaxf(v, 0.f);
                C[(size_t)row * ldc + col] = f2bf(v);
            }
        }
    }
}

// ---------------------------------------------------------------------------
// FUSED qkv + attention per tree. Block = 1 tree (128 tokens), 4 waves.
// X staged in LDS; per head: 3 MFMA passes (B-frags direct from global/L2)
// -> Qs/Ks/Vt in LDS -> R12-verified attention body -> O to global.
// LDS: X 67.6K + Qs 18.4K + Ks 18.4K + Vt 17.4K + Ps 34.8K = 153 KB.
// ---------------------------------------------------------------------------
__global__ __launch_bounds__(256, 1) void k_qkv_attn(
        const u16* __restrict__ x, const u16* __restrict__ Wq,
        const float* __restrict__ bias, size_t biasoff,
        u16* __restrict__ O)
{
    __shared__ __align__(16) u16 Xs[128 * 264];
    __shared__ __align__(16) u16 Qs[128 * 72];
    __shared__ __align__(16) u16 Ksh[128 * 72];
    __shared__ __align__(16) u16 Vtr[64 * 136];
    __shared__ __align__(16) u16 Ps[4][32 * 136];

    int tid = threadIdx.x;
    int w = tid >> 6, lane = tid & 63;
    int ln15 = lane & 15, quad = lane >> 4;
    size_t tok0 = (size_t)blockIdx.x * 128;

    // stage X tile (128 x 256, stride 264)
#pragma unroll
    for (int s = 0; s < 16; ++s) {
        int idx = tid + s * 256;
        int r = idx >> 5, c8 = (idx & 31) * 8;
        *reinterpret_cast<uint4*>(&Xs[r * 264 + c8]) =
            *reinterpret_cast<const uint4*>(&x[(tok0 + r) * 256 + c8]);
    }
    __syncthreads();

    for (int hd = 0; hd < 4; ++hd) {
        // ---- qkv passes: sel 0=Q, 1=K, 2=V ----
        for (int sel = 0; sel < 3; ++sel) {
            const u16* Wb = Wq + ((size_t)(sel * 256 + hd * 64)) * 256;
            f32x4 acc[2][4];
#pragma unroll
            for (int i = 0; i < 2; ++i)
#pragma unroll
                for (int jt = 0; jt < 4; ++jt)
#pragma unroll
                    for (int r = 0; r < 4; ++r) acc[i][jt][r] = 0.f;

#pragma unroll
            for (int kk = 0; kk < 8; ++kk) {
                bf16x8 a0 = *reinterpret_cast<const bf16x8*>(
                    &Xs[(w * 32 + ln15) * 264 + kk * 32 + quad * 8]);
                bf16x8 a1 = *reinterpret_cast<const bf16x8*>(
                    &Xs[(w * 32 + 16 + ln15) * 264 + kk * 32 + quad * 8]);
#pragma unroll
                for (int jt = 0; jt < 4; ++jt) {
                    bf16x8 b = *reinterpret_cast<const bf16x8*>(
                        &Wb[(size_t)(jt * 16 + ln15) * 256 + kk * 32 + quad * 8]);
                    acc[0][jt] = __builtin_amdgcn_mfma_f32_16x16x32_bf16(
                        a0, b, acc[0][jt], 0, 0, 0);
                    acc[1][jt] = __builtin_amdgcn_mfma_f32_16x16x32_bf16(
                        a1, b, acc[1][jt], 0, 0, 0);
                }
            }
#pragma unroll
            for (int i = 0; i < 2; ++i)
#pragma unroll
                for (int jt = 0; jt < 4; ++jt) {
                    int col = jt * 16 + ln15;
                    float bv = bias[biasoff + sel * 256 + hd * 64 + col];
#pragma unroll
                    for (int r = 0; r < 4; ++r) {
                        int row = w * 32 + i * 16 + quad * 4 + r;
                        float v = acc[i][jt][r] + bv;
                        if (sel == 0)      Qs[row * 72 + col] = f2bf(v);
                        else if (sel == 1) Ksh[row * 72 + col] = f2bf(v);
                        else               Vtr[col * 136 + row] = f2bf(v);
                    }
                }
        }
        __syncthreads();

        // ---- attention (R12-verified body; Q from LDS) ----
        bf16x8 qf[2][2];
#pragma unroll
        for (int i = 0; i < 2; ++i)
#pragma unroll
            for (int kk = 0; kk < 2; ++kk)
                qf[i][kk] = *reinterpret_cast<const bf16x8*>(
                    &Qs[(w * 32 + i * 16 + ln15) * 72 + kk * 32 + quad * 8]);

        f32x4 sa[2][8];
#pragma unroll
        for (int i = 0; i < 2; ++i)
#pragma unroll
            for (int j = 0; j < 8; ++j)
#pragma unroll
                for (int r = 0; r < 4; ++r) sa[i][j][r] = 0.f;

#pragma unroll
        for (int j = 0; j < 8; ++j)
#pragma unroll
            for (int kk = 0; kk < 2; ++kk) {
                bf16x8 kf = *reinterpret_cast<const bf16x8*>(
                    &Ksh[(j * 16 + ln15) * 72 + kk * 32 + quad * 8]);
                sa[0][j] = __builtin_amdgcn_mfma_f32_16x16x32_bf16(qf[0][kk], kf, sa[0][j], 0, 0, 0);
                sa[1][j] = __builtin_amdgcn_mfma_f32_16x16x32_bf16(qf[1][kk], kf, sa[1][j], 0, 0, 0);
            }

        const float scale = 0.125f;
#pragma unroll
        for (int i = 0; i < 2; ++i) {
#pragma unroll
            for (int r = 0; r < 4; ++r) {
                float m = -3e38f;
#pragma unroll
                for (int j = 0; j < 8; ++j) m = fmaxf(m, sa[i][j][r]);
                m = fmaxf(m, __shfl_xor(m, 1, 64));
                m = fmaxf(m, __shfl_xor(m, 2, 64));
                m = fmaxf(m, __shfl_xor(m, 4, 64));
                m = fmaxf(m, __shfl_xor(m, 8, 64));
                m *= scale;
                float p[8];
                float l = 0.f;
#pragma unroll
                for (int j = 0; j < 8; ++j) {
                    p[j] = __expf(sa[i][j][r] * scale - m);
                    l += p[j];
                }
                l += __shfl_xor(l, 1, 64);
                l += __shfl_xor(l, 2, 64);
                l += __shfl_xor(l, 4, 64);
                l += __shfl_xor(l, 8, 64);
                float inv = 1.f / l;
                int row = i * 16 + quad * 4 + r;
#pragma unroll
                for (int j = 0; j < 8; ++j)
                    Ps[w][row * 136 + j * 16 + ln15] = f2bf(p[j] * inv);
            }
        }

        f32x4 oa[2][4];
#pragma unroll
        for (int i = 0; i < 2; ++i)
#pragma unroll
            for (int jt = 0; jt < 4; ++jt)
#pragma unroll
                for (int r = 0; r < 4; ++r) oa[i][jt][r] = 0.f;

#pragma unroll
        for (int ks = 0; ks < 4; ++ks) {
            bf16x8 pf0 = *reinterpret_cast<const bf16x8*>(
                &Ps[w][(0 + ln15) * 136 + ks * 32 + quad * 8]);
            bf16x8 pf1 = *reinterpret_cast<const bf16x8*>(
                &Ps[w][(16 + ln15) * 136 + ks * 32 + quad * 8]);
#pragma unroll
            for (int jt = 0; jt < 4; ++jt) {
                bf16x8 vf = *reinterpret_cast<const bf16x8*>(
                    &Vtr[(jt * 16 + ln15) * 136 + ks * 32 + quad * 8]);
                oa[0][jt] = __builtin_amdgcn_mfma_f32_16x16x32_bf16(pf0, vf, oa[0][jt], 0, 0, 0);
                oa[1][jt] = __builtin_amdgcn_mfma_f32_16x16x32_bf16(pf1, vf, oa[1][jt], 0, 0, 0);
            }
        }

#pragma unroll
        for (int i = 0; i < 2; ++i)
#pragma unroll
            for (int jt = 0; jt < 4; ++jt)
#pragma unroll
                for (int r = 0; r < 4; ++r) {
                    int row = w * 32 + i * 16 + quad * 4 + r;
                    int d = jt * 16 + ln15;
                    O[(tok0 + row) * 256 + hd * 64 + d] = f2bf(oa[i][jt][r]);
                }
        __syncthreads();   // before next head overwrites Qs/Ks/Vt
    }
}

// ---------------------------------------------------------------------------
// MFMA final projection (verified R15).
// ---------------------------------------------------------------------------
__global__ __launch_bounds__(256) void k_gemm_fin(
        const u16* __restrict__ A, const u16* __restrict__ Bw,
        float* __restrict__ C, int kchunk)
{
    __shared__ __align__(16) u16 As[64][72];
    __shared__ __align__(16) u16 Bs[64][72];

    int tid = threadIdx.x;
    int w = tid >> 6, lane = tid & 63;
    int ln15 = lane & 15, quad = lane >> 4;
    size_t m0 = (size_t)blockIdx.x * 64;
    int k0 = blockIdx.y * kchunk;

    f32x4 acc[4];
#pragma unroll
    for (int j = 0; j < 4; ++j)
#pragma unroll
        for (int r = 0; r < 4; ++r) acc[j][r] = 0.f;

    for (int kk = k0; kk < k0 + kchunk; kk += 64) {
        __syncthreads();
#pragma unroll
        for (int s = 0; s < 2; ++s) {
            int idx = tid + s * 256;
            int r = idx >> 3;
            int c8 = (idx & 7) * 8;
            *reinterpret_cast<uint4*>(&As[r][c8]) =
                *reinterpret_cast<const uint4*>(&A[(m0 + r) * 32768 + kk + c8]);
            *reinterpret_cast<uint4*>(&Bs[r][c8]) =
                *reinterpret_cast<const uint4*>(&Bw[(size_t)r * 32768 + kk + c8]);
        }
        __syncthreads();

        bf16x8 af[2];
#pragma unroll
        for (int kh = 0; kh < 2; ++kh)
            af[kh] = *reinterpret_cast<const bf16x8*>(
                &As[w * 16 + ln15][kh * 32 + quad * 8]);
#pragma unroll
        for (int j = 0; j < 4; ++j)
#pragma unroll
            for (int kh = 0; kh < 2; ++kh) {
                bf16x8 bf = *reinterpret_cast<const bf16x8*>(
                    &Bs[j * 16 + ln15][kh * 32 + quad * 8]);
                acc[j] = __builtin_amdgcn_mfma_f32_16x16x32_bf16(
                    af[kh], bf, acc[j], 0, 0, 0);
            }
    }

#pragma unroll
    for (int j = 0; j < 4; ++j)
#pragma unroll
        for (int r = 0; r < 4; ++r) {
            int row = (int)m0 + w * 16 + quad * 4 + r;
            int col = j * 16 + ln15;
            atomicAdd(&C[(size_t)row * OUT_ + col], acc[j][r]);
        }
}

// ---------------------------------------------------------------------------
// x = LayerNorm(x + res) * w + b — wave-per-row (verified R13).
// ---------------------------------------------------------------------------
__global__ __launch_bounds__(256) void k_ln(
        u16* __restrict__ x, const u16* __restrict__ res, int rld,
        const float* __restrict__ w, const float* __restrict__ b, size_t woff)
{
    int row = blockIdx.x * 4 + (threadIdx.x >> 6);
    int lane = threadIdx.x & 63;
    u16* xr = x + (size_t)row * H_;
    const u16* rr = res + (size_t)row * rld;

    ushort4 xv = *reinterpret_cast<const ushort4*>(&xr[lane * 4]);
    ushort4 rv = *reinterpret_cast<const ushort4*>(&rr[lane * 4]);
    float v0 = u2f(xv.x) + u2f(rv.x);
    float v1 = u2f(xv.y) + u2f(rv.y);
    float v2 = u2f(xv.z) + u2f(rv.z);
    float v3 = u2f(xv.w) + u2f(rv.w);

    float s = v0 + v1 + v2 + v3;
#pragma unroll
    for (int o = 32; o > 0; o >>= 1) s += __shfl_xor(s, o, 64);
    float mu = s * (1.f / 256.f);
    float d0 = v0 - mu, d1 = v1 - mu, d2 = v2 - mu, d3 = v3 - mu;
    float s2 = d0 * d0 + d1 * d1 + d2 * d2 + d3 * d3;
#pragma unroll
    for (int o = 32; o > 0; o >>= 1) s2 += __shfl_xor(s2, o, 64);
    float rstd = rsqrtf(s2 * (1.f / 256.f) + 1e-5f);

    float4 wv = *reinterpret_cast<const float4*>(&w[woff + lane * 4]);
    float4 bv = *reinterpret_cast<const float4*>(&b[woff + lane * 4]);
    ushort4 ov;
    ov.x = f2bf(d0 * rstd * wv.x + bv.x);
    ov.y = f2bf(d1 * rstd * wv.y + bv.y);
    ov.z = f2bf(d2 * rstd * wv.z + bv.z);
    ov.w = f2bf(d3 * rstd * wv.w + bv.w);
    *reinterpret_cast<ushort4*>(&xr[lane * 4]) = ov;
}

// ---------------------------------------------------------------------------
__global__ __launch_bounds__(256) void k_zero(float* __restrict__ p, int n)
{
    int i = blockIdx.x * 256 + threadIdx.x;
    if (i < n) p[i] = 0.f;
}

// ---------------------------------------------------------------------------
// out = LayerNorm(Cf[row,:] + b_out) * lnf_w + lnf_b -> fp32 (verified R9)
// ---------------------------------------------------------------------------
__global__ __launch_bounds__(256) void k_lnf(
        const float* __restrict__ C, const float* __restrict__ b_out,
        const float* __restrict__ w, const float* __restrict__ b,
        float* __restrict__ out)
{
    int row = blockIdx.x * 256 + threadIdx.x;
    if (row >= T_) return;
    const float* cr = C + (size_t)row * OUT_;

    float s = 0.f;
    for (int o = 0; o < OUT_; ++o) s += cr[o] + b_out[o];
    float mu = s * (1.f / OUT_);
    float s2 = 0.f;
    for (int o = 0; o < OUT_; ++o) {
        float d = cr[o] + b_out[o] - mu;
        s2 += d * d;
    }
    float rstd = rsqrtf(s2 * (1.f / OUT_) + 1e-5f);
    for (int o = 0; o < OUT_; ++o) {
        float d = cr[o] + b_out[o] - mu;
        out[(size_t)row * OUT_ + o] = d * rstd * w[o] + b[o];
    }
}

// ---------------------------------------------------------------------------
extern "C" void kernel_launch(void* const* d_in, const int* in_sizes, int n_in,
                              void* d_out, int out_size, void* d_ws, size_t ws_size,
                              hipStream_t stream)
{
    static const int szA[23] = {
        1048576, 195072, 65536, 4096, 256, 98304, 256, 393216, 1536,
        131072, 512, 512, 512, 262144, 1024, 262144, 512, 512, 512,
        2097152, 64, 64, 64};
    static const int mapB[23] = {
        11, 3, 18, 0, 4, 2, 6, 22, 21, 20, 19, 13, 12, 8, 7, 10, 9,
        15, 14, 1, 5, 16, 17};
    bool isA = (n_in >= 23);
    for (int i = 0; i < 23 && i < n_in; ++i)
        if (in_sizes[i] != szA[i]) isA = false;
    const void* in[23];
    for (int i = 0; i < 23; ++i)
        in[i] = isA ? d_in[i] : d_in[mapB[i]];

    const float* forest = (const float*)in[0];
    const int*   adj    = (const int*)in[1];
    const float* W_in   = (const float*)in[3];
    const float* b_in   = (const float*)in[4];
    const float* W_pos  = (const float*)in[5];
    const float* b_pos  = (const float*)in[6];
    const float* qkv_w  = (const float*)in[7];
    const float* qkv_b  = (const float*)in[8];
    const float* outp_w = (const float*)in[9];
    const float* outp_b = (const float*)in[10];
    const float* ln1_w  = (const float*)in[11];
    const float* ln1_b  = (const float*)in[12];
    const float* ff1_w  = (const float*)in[13];
    const float* ff1_b  = (const float*)in[14];
    const float* ff2_w  = (const float*)in[15];
    const float* ff2_b  = (const float*)in[16];
    const float* ln2_w  = (const float*)in[17];
    const float* ln2_b  = (const float*)in[18];
    const float* W_out  = (const float*)in[19];
    const float* b_out  = (const float*)in[20];
    const float* lnf_w  = (const float*)in[21];
    const float* lnf_b  = (const float*)in[22];

    // ---- ws layout: mask | xb | wb (bf16, incl W_out) | prep f32 | cbuf ----
    int* mask = (int*)d_ws;                              // 256 KiB
    u16* xb   = (u16*)((char*)d_ws + (size_t)TOK_ * 4);  // 32 MiB
    u16* wb   = xb + (size_t)TOK_ * H_;                  // 6 MiB bf16 weights
    const size_t WB_QKV  = 0;
    const size_t WB_OUT  = 393216;
    const size_t WB_FF1  = 524288;
    const size_t WB_FF2  = 786432;
    const size_t WB_WOUT = 1048576;                      // 2097152 u16
    const size_t WB_TOT  = 1048576 + 2097152;            // 3145728 u16
    float* prep  = (float*)(wb + WB_TOT);                // 33 KiB
    float* bsum  = prep;                                 // 256
    float* W_inT = prep + 256;                           // 4096
    float* W_posT= prep + 256 + 4096;                    // 4096 (p<16)
    u16* cbuf = (u16*)(prep + 256 + 4096 + 4096);        // rows x 768 bf16
    size_t used = (size_t)TOK_ * 4 + (size_t)TOK_ * H_ * 2 + WB_TOT * 2
                + (256 + 4096 + 4096) * 4;
    size_t avail = (ws_size > used) ? ws_size - used : 0;
    size_t max_rows = avail / (768 * 2);
    int rc = (int)((max_rows / 128) * 128);
    if (rc > TOK_) rc = TOK_;
    if (rc < 128) rc = 128;

    // weight conversion fp32 -> bf16 + init-prep (per launch)
    k_cvt<<<512, 256, 0, stream>>>(qkv_w,  wb + WB_QKV, 393216);
    k_cvt<<<256, 256, 0, stream>>>(outp_w, wb + WB_OUT, 131072);
    k_cvt<<<512, 256, 0, stream>>>(ff1_w,  wb + WB_FF1, 262144);
    k_cvt<<<512, 256, 0, stream>>>(ff2_w,  wb + WB_FF2, 262144);
    k_cvt<<<1024, 256, 0, stream>>>(W_out, wb + WB_WOUT, 2097152);
    k_prep<<<16, 256, 0, stream>>>(W_in, b_in, b_pos, W_pos,
                                   W_inT, W_posT, bsum);

    // pos bitmasks (per-node ancestor walk), then x0 (coalesced init)
    k_pos<<<TOK_ / 256, 256, 0, stream>>>(adj, mask);
    k_init_x<<<TOK_ / 4, 256, 0, stream>>>(forest, mask, W_inT, W_posT,
                                           bsum, xb);

    // transformer layers, chunked over whole trees
    for (int R0 = 0; R0 < TOK_; R0 += rc) {
        int rows = (TOK_ - R0 < rc) ? (TOK_ - R0) : rc;   // multiple of 128
        u16* xc   = xb + (size_t)R0 * H_;
        u16* Oc   = cbuf;                       // rows x 256 (attn out)
        u16* Poutc= cbuf + (size_t)rows * 256;  // rows x 256 (proj out)
        u16* hc   = cbuf;                       // rows x 512 (O/Pout dead)
        u16* h2c  = cbuf + (size_t)rows * 512;  // rows x 256 (tail)

        for (int l = 0; l < L_; ++l) {
            // fused qkv + attention -> Oc
            k_qkv_attn<<<rows / 128, 256, 0, stream>>>(
                xc, wb + WB_QKV + (size_t)l * 768 * 256,
                qkv_b, (size_t)l * 768, Oc);
            // proj = O @ outp_w[l]^T + outp_b[l] -> Poutc
            k_gemm_mfma<<<dim3(rows / 128, 256 / 128), 256, 0, stream>>>(
                Oc, 256, wb + WB_OUT + (size_t)l * 256 * 256, 256,
                outp_b, (size_t)l * 256, Poutc, 256, 256, 0);
            // x = LN(x + proj)
            k_ln<<<rows / 4, 256, 0, stream>>>(xc, Poutc, 256,
                                               ln1_w, ln1_b, (size_t)l * 256);
            // h = relu(x @ ff1_w[l]^T + ff1_b[l])
            k_gemm_mfma<<<dim3(rows / 128, 512 / 128), 256, 0, stream>>>(
                xc, H_, wb + WB_FF1 + (size_t)l * 512 * 256, 256,
                ff1_b, (size_t)l * 512, hc, 512, 256, 1);
            // h2 = h @ ff2_w[l]^T + ff2_b[l]
            k_gemm_mfma<<<dim3(rows / 128, 256 / 128), 256, 0, stream>>>(
                hc, 512, wb + WB_FF2 + (size_t)l * 256 * 512, 512,
                ff2_b, (size_t)l * 256, h2c, 256, 512, 0);
            // x = LN(x + h2)
            k_ln<<<rows / 4, 256, 0, stream>>>(xc, h2c, 256,
                                               ln2_w, ln2_b, (size_t)l * 256);
        }
    }

    // final: Cf = x.reshape(512, 32768) @ W_out^T (MFMA, split-K=32, atomic)
    float* Cf = (float*)cbuf;                  // 128 KiB, cbuf dead
    k_zero<<<(T_ * OUT_ + 255) / 256, 256, 0, stream>>>(Cf, T_ * OUT_);
    k_gemm_fin<<<dim3(T_ / 64, 32), 256, 0, stream>>>(
        xb, wb + WB_WOUT, Cf, 1024);
    // out = LN(Cf + b_out) -> fp32
    k_lnf<<<(T_ + 255) / 256, 256, 0, stream>>>(Cf, b_out, lnf_w, lnf_b,
                                                (float*)d_out);
}

// Round 17
// 690.754 us; speedup vs baseline: 1.1141x; 1.1141x over previous
//
#include <hip/hip_runtime.h>

#define B_    128
#define A_    4
#define N_    128
#define F_IN_ 16
#define H_    256
#define HEADS_ 4
#define FF_   512
#define OUT_  64
#define BF_   3
#define L_    2
#define T_    512          // B*A
#define E_    127          // N-1
#define DH_   64
#define P_    384          // N*BF
#define TOK_  65536        // T*N

typedef unsigned short u16;
typedef __attribute__((ext_vector_type(8))) short bf16x8;   // 8 bf16 = 4 VGPR
typedef __attribute__((ext_vector_type(4))) float f32x4;

__device__ __forceinline__ float u2f(u16 u) {
    return __uint_as_float(((unsigned)u) << 16);
}
__device__ __forceinline__ u16 f2bf(float f) {
    unsigned u = __float_as_uint(f);
    unsigned r = (u + 0x7fffu + ((u >> 16) & 1u)) >> 16;
    return (u16)r;
}

// ---------------------------------------------------------------------------
// fp32 -> bf16 weight conversion (grid-stride)
// ---------------------------------------------------------------------------
__global__ __launch_bounds__(256) void k_cvt(
        const float* __restrict__ src, u16* __restrict__ dst, int n)
{
    for (int i = blockIdx.x * 256 + threadIdx.x; i < n; i += gridDim.x * 256)
        dst[i] = f2bf(src[i]);
}

// ---------------------------------------------------------------------------
// init-weight prep (verified R13)
// ---------------------------------------------------------------------------
__global__ __launch_bounds__(256) void k_prep(
        const float* __restrict__ W_in, const float* __restrict__ b_in,
        const float* __restrict__ b_pos, const float* __restrict__ W_pos,
        float* __restrict__ W_inT, float* __restrict__ W_posT,
        float* __restrict__ bsum)
{
    int i = blockIdx.x * 256 + threadIdx.x;
    if (i < 4096) W_inT[(i & 15) * 256 + (i >> 4)] = W_in[i];
    if (i < 4096) {
        int p = i >> 8, h = i & 255;
        W_posT[i] = W_pos[(size_t)h * P_ + p];
    }
    if (i < 256) bsum[i] = b_in[i] + b_pos[i];
}

// ---------------------------------------------------------------------------
// pos bitmask per node (verified R14)
// ---------------------------------------------------------------------------
__global__ __launch_bounds__(256) void k_pos(
        const int* __restrict__ adj, int* __restrict__ mask)
{
    int tn = blockIdx.x * 256 + threadIdx.x;
    if (tn >= TOK_) return;
    int t = tn >> 7;
    int n = tn & 127;

    int slots[8];
    int nb = 0;
    int c = n;
    while (c > 0 && nb < 8) {
        const int* e = adj + ((size_t)t * E_ + (c - 1)) * 3;
        int pg = e[0];
        int sl = e[2] + 1;
        sl = sl < 0 ? 0 : (sl > 2 ? 2 : sl);
        slots[nb++] = sl;
        c = pg - t * N_;
    }
    int mk = 0;
    for (int i = 0; i < nb; ++i)
        mk |= 1 << ((nb - 1 - i) * BF_ + slots[i]);
    mask[tn] = mk;
}

// ---------------------------------------------------------------------------
// x0 init, coalesced (verified R13)
// ---------------------------------------------------------------------------
__global__ __launch_bounds__(256) void k_init_x(
        const float* __restrict__ forest, const int* __restrict__ mask,
        const float* __restrict__ W_inT, const float* __restrict__ W_posT,
        const float* __restrict__ bsum, u16* __restrict__ x)
{
    int h = threadIdx.x;
    int t0 = blockIdx.x * 4;

    float wf[16];
#pragma unroll
    for (int f = 0; f < F_IN_; ++f) wf[f] = W_inT[f * 256 + h];
    float bs = bsum[h];

#pragma unroll
    for (int tt = 0; tt < 4; ++tt) {
        int tn = t0 + tt;
        const float* fr = forest + (size_t)tn * F_IN_;
        float acc = bs;
#pragma unroll
        for (int f = 0; f < F_IN_; ++f) acc += fr[f] * wf[f];
        unsigned mk = (unsigned)mask[tn];
        while (mk) {
            int bit = __ffs(mk) - 1;
            mk &= mk - 1;
            acc += W_posT[bit * 256 + h];
        }
        x[(size_t)tn * H_ + h] = f2bf(acc);
    }
}

// ---------------------------------------------------------------------------
// MFMA GEMM (verified R11). Grid: x = N-block, y = M-block (L2-friendly:
// co-resident blocks share the same A row-tile -> A fetched ~once).
// ---------------------------------------------------------------------------
__global__ __launch_bounds__(256) void k_gemm_mfma(
        const u16* __restrict__ A, int lda,
        const u16* __restrict__ Bw, int ldb,
        const float* __restrict__ bias, size_t biasoff,
        u16* __restrict__ C, int ldc,
        int K, int relu)
{
    __shared__ __align__(16) u16 As[128][40];
    __shared__ __align__(16) u16 Bs[128][40];

    int tid = threadIdx.x;
    int wid = tid >> 6, lane = tid & 63;
    int ln15 = lane & 15, quad = lane >> 4;
    int wm = (wid >> 1) * 64, wn = (wid & 1) * 64;
    size_t m0 = (size_t)blockIdx.y * 128;
    size_t n0 = (size_t)blockIdx.x * 128;

    f32x4 acc[4][4];
#pragma unroll
    for (int i = 0; i < 4; ++i)
#pragma unroll
        for (int j = 0; j < 4; ++j)
#pragma unroll
            for (int r = 0; r < 4; ++r) acc[i][j][r] = 0.f;

    for (int k0 = 0; k0 < K; k0 += 32) {
        __syncthreads();
#pragma unroll
        for (int s = 0; s < 2; ++s) {
            int idx = tid + s * 256;
            int r = idx >> 2;
            int kq = (idx & 3) * 8;
            *reinterpret_cast<uint4*>(&As[r][kq]) =
                *reinterpret_cast<const uint4*>(&A[(m0 + r) * (size_t)lda + k0 + kq]);
            *reinterpret_cast<uint4*>(&Bs[r][kq]) =
                *reinterpret_cast<const uint4*>(&Bw[(n0 + r) * (size_t)ldb + k0 + kq]);
        }
        __syncthreads();

        bf16x8 af[4], bfr[4];
#pragma unroll
        for (int i = 0; i < 4; ++i)
            af[i] = *reinterpret_cast<const bf16x8*>(&As[wm + i * 16 + ln15][quad * 8]);
#pragma unroll
        for (int j = 0; j < 4; ++j)
            bfr[j] = *reinterpret_cast<const bf16x8*>(&Bs[wn + j * 16 + ln15][quad * 8]);
#pragma unroll
        for (int i = 0; i < 4; ++i)
#pragma unroll
            for (int j = 0; j < 4; ++j)
                acc[i][j] = __builtin_amdgcn_mfma_f32_16x16x32_bf16(
                    af[i], bfr[j], acc[i][j], 0, 0, 0);
    }

#pragma unroll
    for (int i = 0; i < 4; ++i) {
#pragma unroll
        for (int j = 0; j < 4; ++j) {
            int col = (int)n0 + wn + j * 16 + ln15;
            float bv = bias ? bias[biasoff + col] : 0.f;
#pragma unroll
            for (int r = 0; r < 4; ++r) {
                int row = (int)m0 + wm + i * 16 + quad * 4 + r;
                float v = acc[i][j][r] + bv;
                if (relu) v = fmaxf(v, 0.f);
                C[(size_t)row * ldc + col] = f2bf(v);
            }
        }
    }
}

// ---------------------------------------------------------------------------
// MFMA attention per (tree, head) — verified R12.
// ---------------------------------------------------------------------------
__global__ __launch_bounds__(256) void k_attn_mfma(u16* __restrict__ qkv)
{
    __shared__ __align__(16) u16 Ks[128 * 72];
    __shared__ __align__(16) u16 Vt[64 * 136];
    __shared__ __align__(16) u16 Ps[4][32 * 136];

    int blk = blockIdx.x;
    int t = blk >> 2, hd = blk & 3;
    int tid = threadIdx.x;
    int w = tid >> 6, lane = tid & 63;
    int ln15 = lane & 15, quad = lane >> 4;
    u16* base = qkv + (size_t)t * 128 * 768;

    for (int idx = tid; idx < 128 * 16; idx += 256) {
        int r = idx >> 4, d4 = (idx & 15) << 2;
        *reinterpret_cast<ushort4*>(&Ks[r * 72 + d4]) =
            *reinterpret_cast<const ushort4*>(&base[r * 768 + 256 + hd * 64 + d4]);
        ushort4 v = *reinterpret_cast<const ushort4*>(&base[r * 768 + 512 + hd * 64 + d4]);
        Vt[(d4 + 0) * 136 + r] = v.x;
        Vt[(d4 + 1) * 136 + r] = v.y;
        Vt[(d4 + 2) * 136 + r] = v.z;
        Vt[(d4 + 3) * 136 + r] = v.w;
    }

    bf16x8 qf[2][2];
#pragma unroll
    for (int i = 0; i < 2; ++i)
#pragma unroll
        for (int kk = 0; kk < 2; ++kk)
            qf[i][kk] = *reinterpret_cast<const bf16x8*>(
                &base[(size_t)(w * 32 + i * 16 + ln15) * 768 + hd * 64 + kk * 32 + quad * 8]);
    __syncthreads();

    f32x4 sa[2][8];
#pragma unroll
    for (int i = 0; i < 2; ++i)
#pragma unroll
        for (int j = 0; j < 8; ++j)
#pragma unroll
            for (int r = 0; r < 4; ++r) sa[i][j][r] = 0.f;

#pragma unroll
    for (int j = 0; j < 8; ++j)
#pragma unroll
        for (int kk = 0; kk < 2; ++kk) {
            bf16x8 kf = *reinterpret_cast<const bf16x8*>(
                &Ks[(j * 16 + ln15) * 72 + kk * 32 + quad * 8]);
            sa[0][j] = __builtin_amdgcn_mfma_f32_16x16x32_bf16(qf[0][kk], kf, sa[0][j], 0, 0, 0);
            sa[1][j] = __builtin_amdgcn_mfma_f32_16x16x32_bf16(qf[1][kk], kf, sa[1][j], 0, 0, 0);
        }

    const float scale = 0.125f;
#pragma unroll
    for (int i = 0; i < 2; ++i) {
#pragma unroll
        for (int r = 0; r < 4; ++r) {
            float m = -3e38f;
#pragma unroll
            for (int j = 0; j < 8; ++j) m = fmaxf(m, sa[i][j][r]);
            m = fmaxf(m, __shfl_xor(m, 1, 64));
            m = fmaxf(m, __shfl_xor(m, 2, 64));
            m = fmaxf(m, __shfl_xor(m, 4, 64));
            m = fmaxf(m, __shfl_xor(m, 8, 64));
            m *= scale;
            float p[8];
            float l = 0.f;
#pragma unroll
            for (int j = 0; j < 8; ++j) {
                p[j] = __expf(sa[i][j][r] * scale - m);
                l += p[j];
            }
            l += __shfl_xor(l, 1, 64);
            l += __shfl_xor(l, 2, 64);
            l += __shfl_xor(l, 4, 64);
            l += __shfl_xor(l, 8, 64);
            float inv = 1.f / l;
            int row = i * 16 + quad * 4 + r;
#pragma unroll
            for (int j = 0; j < 8; ++j)
                Ps[w][row * 136 + j * 16 + ln15] = f2bf(p[j] * inv);
        }
    }

    f32x4 oa[2][4];
#pragma unroll
    for (int i = 0; i < 2; ++i)
#pragma unroll
        for (int jt = 0; jt < 4; ++jt)
#pragma unroll
            for (int r = 0; r < 4; ++r) oa[i][jt][r] = 0.f;

#pragma unroll
    for (int ks = 0; ks < 4; ++ks) {
        bf16x8 pf0 = *reinterpret_cast<const bf16x8*>(
            &Ps[w][(0 + ln15) * 136 + ks * 32 + quad * 8]);
        bf16x8 pf1 = *reinterpret_cast<const bf16x8*>(
            &Ps[w][(16 + ln15) * 136 + ks * 32 + quad * 8]);
#pragma unroll
        for (int jt = 0; jt < 4; ++jt) {
            bf16x8 vf = *reinterpret_cast<const bf16x8*>(
                &Vt[(jt * 16 + ln15) * 136 + ks * 32 + quad * 8]);
            oa[0][jt] = __builtin_amdgcn_mfma_f32_16x16x32_bf16(pf0, vf, oa[0][jt], 0, 0, 0);
            oa[1][jt] = __builtin_amdgcn_mfma_f32_16x16x32_bf16(pf1, vf, oa[1][jt], 0, 0, 0);
        }
    }

#pragma unroll
    for (int i = 0; i < 2; ++i)
#pragma unroll
        for (int jt = 0; jt < 4; ++jt)
#pragma unroll
            for (int r = 0; r < 4; ++r) {
                int row = w * 32 + i * 16 + quad * 4 + r;
                int d = jt * 16 + ln15;
                base[(size_t)row * 768 + hd * 64 + d] = f2bf(oa[i][jt][r]);
            }
}

// ---------------------------------------------------------------------------
// MFMA final projection (verified R15).
// ---------------------------------------------------------------------------
__global__ __launch_bounds__(256) void k_gemm_fin(
        const u16* __restrict__ A, const u16* __restrict__ Bw,
        float* __restrict__ C, int kchunk)
{
    __shared__ __align__(16) u16 As[64][72];
    __shared__ __align__(16) u16 Bs[64][72];

    int tid = threadIdx.x;
    int w = tid >> 6, lane = tid & 63;
    int ln15 = lane & 15, quad = lane >> 4;
    size_t m0 = (size_t)blockIdx.x * 64;
    int k0 = blockIdx.y * kchunk;

    f32x4 acc[4];
#pragma unroll
    for (int j = 0; j < 4; ++j)
#pragma unroll
        for (int r = 0; r < 4; ++r) acc[j][r] = 0.f;

    for (int kk = k0; kk < k0 + kchunk; kk += 64) {
        __syncthreads();
#pragma unroll
        for (int s = 0; s < 2; ++s) {
            int idx = tid + s * 256;
            int r = idx >> 3;
            int c8 = (idx & 7) * 8;
            *reinterpret_cast<uint4*>(&As[r][c8]) =
                *reinterpret_cast<const uint4*>(&A[(m0 + r) * 32768 + kk + c8]);
            *reinterpret_cast<uint4*>(&Bs[r][c8]) =
                *reinterpret_cast<const uint4*>(&Bw[(size_t)r * 32768 + kk + c8]);
        }
        __syncthreads();

        bf16x8 af[2];
#pragma unroll
        for (int kh = 0; kh < 2; ++kh)
            af[kh] = *reinterpret_cast<const bf16x8*>(
                &As[w * 16 + ln15][kh * 32 + quad * 8]);
#pragma unroll
        for (int j = 0; j < 4; ++j)
#pragma unroll
            for (int kh = 0; kh < 2; ++kh) {
                bf16x8 bf = *reinterpret_cast<const bf16x8*>(
                    &Bs[j * 16 + ln15][kh * 32 + quad * 8]);
                acc[j] = __builtin_amdgcn_mfma_f32_16x16x32_bf16(
                    af[kh], bf, acc[j], 0, 0, 0);
            }
    }

#pragma unroll
    for (int j = 0; j < 4; ++j)
#pragma unroll
        for (int r = 0; r < 4; ++r) {
            int row = (int)m0 + w * 16 + quad * 4 + r;
            int col = j * 16 + ln15;
            atomicAdd(&C[(size_t)row * OUT_ + col], acc[j][r]);
        }
}

// ---------------------------------------------------------------------------
// x = LayerNorm(x + res) * w + b — wave-per-row (verified R13).
// ---------------------------------------------------------------------------
__global__ __launch_bounds__(256) void k_ln(
        u16* __restrict__ x, const u16* __restrict__ res, int rld,
        const float* __restrict__ w, const float* __restrict__ b, size_t woff)
{
    int row = blockIdx.x * 4 + (threadIdx.x >> 6);
    int lane = threadIdx.x & 63;
    u16* xr = x + (size_t)row * H_;
    const u16* rr = res + (size_t)row * rld;

    ushort4 xv = *reinterpret_cast<const ushort4*>(&xr[lane * 4]);
    ushort4 rv = *reinterpret_cast<const ushort4*>(&rr[lane * 4]);
    float v0 = u2f(xv.x) + u2f(rv.x);
    float v1 = u2f(xv.y) + u2f(rv.y);
    float v2 = u2f(xv.z) + u2f(rv.z);
    float v3 = u2f(xv.w) + u2f(rv.w);

    float s = v0 + v1 + v2 + v3;
#pragma unroll
    for (int o = 32; o > 0; o >>= 1) s += __shfl_xor(s, o, 64);
    float mu = s * (1.f / 256.f);
    float d0 = v0 - mu, d1 = v1 - mu, d2 = v2 - mu, d3 = v3 - mu;
    float s2 = d0 * d0 + d1 * d1 + d2 * d2 + d3 * d3;
#pragma unroll
    for (int o = 32; o > 0; o >>= 1) s2 += __shfl_xor(s2, o, 64);
    float rstd = rsqrtf(s2 * (1.f / 256.f) + 1e-5f);

    float4 wv = *reinterpret_cast<const float4*>(&w[woff + lane * 4]);
    float4 bv = *reinterpret_cast<const float4*>(&b[woff + lane * 4]);
    ushort4 ov;
    ov.x = f2bf(d0 * rstd * wv.x + bv.x);
    ov.y = f2bf(d1 * rstd * wv.y + bv.y);
    ov.z = f2bf(d2 * rstd * wv.z + bv.z);
    ov.w = f2bf(d3 * rstd * wv.w + bv.w);
    *reinterpret_cast<ushort4*>(&xr[lane * 4]) = ov;
}

// ---------------------------------------------------------------------------
__global__ __launch_bounds__(256) void k_zero(float* __restrict__ p, int n)
{
    int i = blockIdx.x * 256 + threadIdx.x;
    if (i < n) p[i] = 0.f;
}

// ---------------------------------------------------------------------------
// out = LayerNorm(Cf[row,:] + b_out) * lnf_w + lnf_b -> fp32 (verified R9)
// ---------------------------------------------------------------------------
__global__ __launch_bounds__(256) void k_lnf(
        const float* __restrict__ C, const float* __restrict__ b_out,
        const float* __restrict__ w, const float* __restrict__ b,
        float* __restrict__ out)
{
    int row = blockIdx.x * 256 + threadIdx.x;
    if (row >= T_) return;
    const float* cr = C + (size_t)row * OUT_;

    float s = 0.f;
    for (int o = 0; o < OUT_; ++o) s += cr[o] + b_out[o];
    float mu = s * (1.f / OUT_);
    float s2 = 0.f;
    for (int o = 0; o < OUT_; ++o) {
        float d = cr[o] + b_out[o] - mu;
        s2 += d * d;
    }
    float rstd = rsqrtf(s2 * (1.f / OUT_) + 1e-5f);
    for (int o = 0; o < OUT_; ++o) {
        float d = cr[o] + b_out[o] - mu;
        out[(size_t)row * OUT_ + o] = d * rstd * w[o] + b[o];
    }
}

// ---------------------------------------------------------------------------
extern "C" void kernel_launch(void* const* d_in, const int* in_sizes, int n_in,
                              void* d_out, int out_size, void* d_ws, size_t ws_size,
                              hipStream_t stream)
{
    static const int szA[23] = {
        1048576, 195072, 65536, 4096, 256, 98304, 256, 393216, 1536,
        131072, 512, 512, 512, 262144, 1024, 262144, 512, 512, 512,
        2097152, 64, 64, 64};
    static const int mapB[23] = {
        11, 3, 18, 0, 4, 2, 6, 22, 21, 20, 19, 13, 12, 8, 7, 10, 9,
        15, 14, 1, 5, 16, 17};
    bool isA = (n_in >= 23);
    for (int i = 0; i < 23 && i < n_in; ++i)
        if (in_sizes[i] != szA[i]) isA = false;
    const void* in[23];
    for (int i = 0; i < 23; ++i)
        in[i] = isA ? d_in[i] : d_in[mapB[i]];

    const float* forest = (const float*)in[0];
    const int*   adj    = (const int*)in[1];
    const float* W_in   = (const float*)in[3];
    const float* b_in   = (const float*)in[4];
    const float* W_pos  = (const float*)in[5];
    const float* b_pos  = (const float*)in[6];
    const float* qkv_w  = (const float*)in[7];
    const float* qkv_b  = (const float*)in[8];
    const float* outp_w = (const float*)in[9];
    const float* outp_b = (const float*)in[10];
    const float* ln1_w  = (const float*)in[11];
    const float* ln1_b  = (const float*)in[12];
    const float* ff1_w  = (const float*)in[13];
    const float* ff1_b  = (const float*)in[14];
    const float* ff2_w  = (const float*)in[15];
    const float* ff2_b  = (const float*)in[16];
    const float* ln2_w  = (const float*)in[17];
    const float* ln2_b  = (const float*)in[18];
    const float* W_out  = (const float*)in[19];
    const float* b_out  = (const float*)in[20];
    const float* lnf_w  = (const float*)in[21];
    const float* lnf_b  = (const float*)in[22];

    // ---- ws layout: mask | xb | wb (bf16, incl W_out) | prep f32 | cbuf ----
    int* mask = (int*)d_ws;                              // 256 KiB
    u16* xb   = (u16*)((char*)d_ws + (size_t)TOK_ * 4);  // 32 MiB
    u16* wb   = xb + (size_t)TOK_ * H_;                  // 6 MiB bf16 weights
    const size_t WB_QKV  = 0;
    const size_t WB_OUT  = 393216;
    const size_t WB_FF1  = 524288;
    const size_t WB_FF2  = 786432;
    const size_t WB_WOUT = 1048576;                      // 2097152 u16
    const size_t WB_TOT  = 1048576 + 2097152;            // 3145728 u16
    float* prep  = (float*)(wb + WB_TOT);                // 33 KiB
    float* bsum  = prep;                                 // 256
    float* W_inT = prep + 256;                           // 4096
    float* W_posT= prep + 256 + 4096;                    // 4096 (p<16)
    u16* cbuf = (u16*)(prep + 256 + 4096 + 4096);        // rows x 768 bf16
    size_t used = (size_t)TOK_ * 4 + (size_t)TOK_ * H_ * 2 + WB_TOT * 2
                + (256 + 4096 + 4096) * 4;
    size_t avail = (ws_size > used) ? ws_size - used : 0;
    size_t max_rows = avail / (768 * 2);
    int rc = (int)((max_rows / 128) * 128);
    if (rc > TOK_) rc = TOK_;
    if (rc < 128) rc = 128;

    // weight conversion fp32 -> bf16 + init-prep (per launch)
    k_cvt<<<512, 256, 0, stream>>>(qkv_w,  wb + WB_QKV, 393216);
    k_cvt<<<256, 256, 0, stream>>>(outp_w, wb + WB_OUT, 131072);
    k_cvt<<<512, 256, 0, stream>>>(ff1_w,  wb + WB_FF1, 262144);
    k_cvt<<<512, 256, 0, stream>>>(ff2_w,  wb + WB_FF2, 262144);
    k_cvt<<<1024, 256, 0, stream>>>(W_out, wb + WB_WOUT, 2097152);
    k_prep<<<16, 256, 0, stream>>>(W_in, b_in, b_pos, W_pos,
                                   W_inT, W_posT, bsum);

    // pos bitmasks (per-node ancestor walk), then x0 (coalesced init)
    k_pos<<<TOK_ / 256, 256, 0, stream>>>(adj, mask);
    k_init_x<<<TOK_ / 4, 256, 0, stream>>>(forest, mask, W_inT, W_posT,
                                           bsum, xb);

    // transformer layers, chunked over whole trees (MFMA GEMMs + MFMA attn)
    for (int R0 = 0; R0 < TOK_; R0 += rc) {
        int rows = (TOK_ - R0 < rc) ? (TOK_ - R0) : rc;   // multiple of 128
        u16* xc  = xb + (size_t)R0 * H_;
        u16* qc  = cbuf;                       // rows x 768
        u16* hc  = cbuf;                       // rows x 512 (reuse, qc dead)
        u16* h2c = cbuf + (size_t)rows * 512;  // rows x 256 (tail)

        for (int l = 0; l < L_; ++l) {
            // qkv = x @ qkv_w[l]^T + qkv_b[l]   (grid: x=N-blocks, y=M-blocks)
            k_gemm_mfma<<<dim3(768 / 128, rows / 128), 256, 0, stream>>>(
                xc, H_, wb + WB_QKV + (size_t)l * 768 * 256, 256,
                qkv_b, (size_t)l * 768, qc, 768, 256, 0);
            // attention in place (O over q slice) — MFMA flash
            k_attn_mfma<<<(rows / 128) * HEADS_, 256, 0, stream>>>(qc);
            // proj = O @ outp_w[l]^T + outp_b[l] -> cols 256..511
            k_gemm_mfma<<<dim3(256 / 128, rows / 128), 256, 0, stream>>>(
                qc, 768, wb + WB_OUT + (size_t)l * 256 * 256, 256,
                outp_b, (size_t)l * 256, qc + 256, 768, 256, 0);
            // x = LN(x + proj)
            k_ln<<<rows / 4, 256, 0, stream>>>(xc, qc + 256, 768,
                                               ln1_w, ln1_b, (size_t)l * 256);
            // h = relu(x @ ff1_w[l]^T + ff1_b[l])
            k_gemm_mfma<<<dim3(512 / 128, rows / 128), 256, 0, stream>>>(
                xc, H_, wb + WB_FF1 + (size_t)l * 512 * 256, 256,
                ff1_b, (size_t)l * 512, hc, 512, 256, 1);
            // h2 = h @ ff2_w[l]^T + ff2_b[l]
            k_gemm_mfma<<<dim3(256 / 128, rows / 128), 256, 0, stream>>>(
                hc, 512, wb + WB_FF2 + (size_t)l * 256 * 512, 512,
                ff2_b, (size_t)l * 256, h2c, 256, 512, 0);
            // x = LN(x + h2)
            k_ln<<<rows / 4, 256, 0, stream>>>(xc, h2c, 256,
                                               ln2_w, ln2_b, (size_t)l * 256);
        }
    }

    // final: Cf = x.reshape(512, 32768) @ W_out^T (MFMA, split-K=32, atomic)
    float* Cf = (float*)cbuf;                  // 128 KiB, cbuf dead
    k_zero<<<(T_ * OUT_ + 255) / 256, 256, 0, stream>>>(Cf, T_ * OUT_);
    k_gemm_fin<<<dim3(T_ / 64, 32), 256, 0, stream>>>(
        xb, wb + WB_WOUT, Cf, 1024);
    // out = LN(Cf + b_out) -> fp32
    k_lnf<<<(T_ + 255) / 256, 256, 0, stream>>>(Cf, b_out, lnf_w, lnf_b,
                                                (float*)d_out);
}